// Round 7
// baseline (388.573 us; speedup 1.0000x reference)
//
#include <hip/hip_runtime.h>

#define NV   20000
#define MAXN 16

// ---------------------------------------------------------------------------
// Mask dtype detection (bool may arrive as int32 / byte / float32).
// flag: 0 = int32 words, 2 = float32 pattern, 1 = byte bool.
// ---------------------------------------------------------------------------
__global__ void detect_mask_kind(const unsigned int* __restrict__ m,
                                 int* __restrict__ flag) {
    if (threadIdx.x == 0 && blockIdx.x == 0) {
        int allint = 1, allflt = 1;
        #pragma unroll 8
        for (int k = 0; k < 64; ++k) {
            unsigned w = m[k];
            if (!(w == 0u || w == 1u)) allint = 0;
            if (!(w == 0u || w == 0x3F800000u)) allflt = 0;
        }
        *flag = allint ? 0 : (allflt ? 2 : 1);
    }
}

// ---------------------------------------------------------------------------
// One-time weight combine: for each thread slot t=(c,i) produce 8 rows of 8
// (WQ, WK, W0, W1o0, W1o1, W2o0, W2o1, W2o2) = 64 floats, contiguous per t.
// 64KB table, L2-resident, shared by all 20000 main blocks.
// ---------------------------------------------------------------------------
__global__ void compute_weights(const float* __restrict__ rr,
                                const float* __restrict__ vb0,
                                const float* __restrict__ vb1,
                                const float* __restrict__ vb2,
                                const float* __restrict__ qc,
                                const float* __restrict__ kc,
                                const float* __restrict__ w0p,
                                const float* __restrict__ w1p,
                                const float* __restrict__ w2p,
                                float4* __restrict__ wt) {
    const int t = threadIdx.x;
    const int c = t & 31;
    const int i = t >> 5;
    float WQr[8], WKr[8], W0r[8], W1r0[8], W1r1[8], W2r0[8], W2r1[8], W2r2[8];
    #pragma unroll
    for (int j = 0; j < 8; ++j) {
        WQr[j] = 0.f; WKr[j] = 0.f; W0r[j] = 0.f; W1r0[j] = 0.f;
        W1r1[j] = 0.f; W2r0[j] = 0.f; W2r1[j] = 0.f; W2r2[j] = 0.f;
    }
    #pragma unroll
    for (int b = 0; b < 8; ++b) {
        const float qcb = qc[c * 8 + b];
        const float kcb = kc[c * 8 + b];
        const float w0b = w0p[c * 8 + b];
        const float w1b = w1p[c * 8 + b];
        const float w2b = w2p[c * 8 + b];
        const float* rrb = rr  + b * 64  + i * 8;
        const float* z0  = vb0 + b * 64  + i * 8;
        const float* z1  = vb1 + b * 128 + i * 8;   // [b][o][i][j]
        const float* z2  = vb2 + b * 192 + i * 8;
        #pragma unroll
        for (int j = 0; j < 8; ++j) {
            const float r = rrb[j];
            WQr[j]  = fmaf(qcb, r, WQr[j]);
            WKr[j]  = fmaf(kcb, r, WKr[j]);
            W0r[j]  = fmaf(w0b, z0[j],       W0r[j]);
            W1r0[j] = fmaf(w1b, z1[j],       W1r0[j]);
            W1r1[j] = fmaf(w1b, z1[64 + j],  W1r1[j]);
            W2r0[j] = fmaf(w2b, z2[j],       W2r0[j]);
            W2r1[j] = fmaf(w2b, z2[64 + j],  W2r1[j]);
            W2r2[j] = fmaf(w2b, z2[128 + j], W2r2[j]);
        }
    }
    float4* o = wt + t * 16;
    o[ 0] = *(const float4*)&WQr[0];  o[ 1] = *(const float4*)&WQr[4];
    o[ 2] = *(const float4*)&WKr[0];  o[ 3] = *(const float4*)&WKr[4];
    o[ 4] = *(const float4*)&W0r[0];  o[ 5] = *(const float4*)&W0r[4];
    o[ 6] = *(const float4*)&W1r0[0]; o[ 7] = *(const float4*)&W1r0[4];
    o[ 8] = *(const float4*)&W1r1[0]; o[ 9] = *(const float4*)&W1r1[4];
    o[10] = *(const float4*)&W2r0[0]; o[11] = *(const float4*)&W2r0[4];
    o[12] = *(const float4*)&W2r1[0]; o[13] = *(const float4*)&W2r1[4];
    o[14] = *(const float4*)&W2r2[0]; o[15] = *(const float4*)&W2r2[4];
}

__device__ __forceinline__ float dot8a(const float* __restrict__ w,
                                       const float* __restrict__ f) {
    float s = w[0] * f[0];
    #pragma unroll
    for (int j = 1; j < 8; ++j) s = fmaf(w[j], f[j], s);
    return s;
}

// reduce over c: sum across the 32 lanes of each 32-lane half
__device__ __forceinline__ float xred32(float v) {
    v += __shfl_xor(v, 1);
    v += __shfl_xor(v, 2);
    v += __shfl_xor(v, 4);
    v += __shfl_xor(v, 8);
    v += __shfl_xor(v, 16);
    return v;
}

// One vertex per block, 20000 blocks. R5 showed VGPR_Count=52: the compiler
// re-loaded the 64-float weight set from L2 at EVERY use (12 dwordx4 per
// neighbor per thread ~ 12.6 TB of L2 traffic ~ the whole 375us runtime).
// Per-element scalar asm "+v" pins (the float4 tied-operand form does not
// compile on gfx950) make each W value an opaque asm result: re-loading from
// wt is no longer provably equivalent, so the values must stay in VGPRs.
__global__ void __launch_bounds__(256, 3)
ge_attn_kernel(const float* __restrict__ x,
               const int*   __restrict__ neighbors,
               const void*  __restrict__ maskp,
               const float* __restrict__ ptm,
               const float* __restrict__ rpu,
               const float4* __restrict__ wt,
               const int*   __restrict__ mflag,
               float*       __restrict__ out) {
    const int t = threadIdx.x;
    const int c = t & 31;   // channel
    const int i = t >> 5;   // rep index 0..7
    const int w = t >> 6;   // wave id 0..3
    const int mf = *mflag;

    // per-thread combined weight rows: 64 floats, pinned in VGPRs.
    // layout: [WQ 0..7][WK 8..15][W0 16..23][W1o0 24..31][W1o1 32..39]
    //         [W2o0 40..47][W2o1 48..55][W2o2 56..63]
    float W[64];
    {
        const float4* wp = wt + t * 16;
        #pragma unroll
        for (int r = 0; r < 16; ++r) {
            const float4 q = wp[r];
            W[r * 4 + 0] = q.x; W[r * 4 + 1] = q.y;
            W[r * 4 + 2] = q.z; W[r * 4 + 3] = q.w;
        }
        #pragma unroll
        for (int r = 0; r < 64; ++r)
            asm volatile("" : "+v"(W[r]));   // anti-remat / anti-reload pin
    }

    __shared__ __align__(16) float swv[16][4];

    const int v  = blockIdx.x;
    const int vq = v * 16;

    // uniform loads: neighbor ids + mask
    int nb[16];
    unsigned livemask = 0;
    #pragma unroll
    for (int n = 0; n < 16; ++n) {
        nb[n] = neighbors[vq + n];
        int mm;
        if (mf == 0)      mm = (((const int*)maskp)[vq + n] != 0);
        else if (mf == 1) mm = (((const unsigned char*)maskp)[vq + n] != 0);
        else              mm = (((const float*)maskp)[vq + n] != 0.0f);
        if (mm) livemask |= (1u << n);
    }

    // K[i] for this thread's i, reduced over c in-wave
    float kreg;
    {
        float xc[8];
        const float* xv = x + (size_t)v * 256 + c * 8;
        *(float4*)&xc[0] = *(const float4*)xv;
        *(float4*)&xc[4] = *(const float4*)(xv + 4);
        kreg = xred32(dot8a(&W[8], xc));
    }

    float vals[16];
    float acc = 0.f, ssum = 0.f;

    #pragma unroll
    for (int n = 0; n < 16; ++n) {
        if (!(livemask & (1u << n))) continue;
        // neighbor feature row (block-uniform row id; 32B/lane, L2/L3)
        float xn[8];
        {
            const float* xnp = x + (size_t)nb[n] * 256 + c * 8;
            *(float4*)&xn[0] = *(const float4*)xnp;
            *(float4*)&xn[4] = *(const float4*)(xnp + 4);
        }
        // transported row f'[c,0:8]; P block-uniform -> s_load operands
        const float* Pp = ptm + (size_t)(vq + n) * 64;
        float f[8];
        #pragma unroll
        for (int j = 0; j < 8; ++j) {
            float p[8];
            *(float4*)&p[0] = *(const float4*)(Pp + j * 8);
            *(float4*)&p[4] = *(const float4*)(Pp + j * 8 + 4);
            f[j] = dot8a(p, xn);
        }
        // score partial: Q[i] over c, relu, i-pair sum in-wave
        const float q = xred32(dot8a(&W[0], f));
        const float r = fmaxf(q + kreg, 0.f);
        const float s = r + __shfl_xor(r, 32);
        if ((t & 63) == 0) swv[n][w] = s;
        // value scalar for this (c,i): 6 dots + u-polynomial
        const float u0 = rpu[(size_t)(vq + n) * 2];
        const float u1 = rpu[(size_t)(vq + n) * 2 + 1];
        const float y0 = dot8a(&W[16], f);
        const float y1 = dot8a(&W[24], f);
        const float y2 = dot8a(&W[32], f);
        const float y3 = dot8a(&W[40], f);
        const float y4 = dot8a(&W[48], f);
        const float y5 = dot8a(&W[56], f);
        float val = fmaf(u0, y1, y0);
        val = fmaf(u1, y2, val);
        val = fmaf(u0 * u0, y3, val);
        val = fmaf(2.f * u0 * u1, y4, val);
        val = fmaf(u1 * u1, y5, val);
        vals[n] = val;
    }

    __syncthreads();   // publish swv

    #pragma unroll
    for (int n = 0; n < 16; ++n) {
        if (!(livemask & (1u << n))) continue;
        const float4 sv = *(const float4*)&swv[n][0];
        const float sc = 0.125f * (sv.x + sv.y + sv.z + sv.w);
        ssum += sc;
        acc  = fmaf(sc, vals[n], acc);
    }
    out[(size_t)v * 256 + c * 8 + i] = acc / fmaxf(ssum, 1e-8f);
}

extern "C" void kernel_launch(void* const* d_in, const int* in_sizes, int n_in,
                              void* d_out, int out_size, void* d_ws, size_t ws_size,
                              hipStream_t stream) {
    const float* x         = (const float*)d_in[0];
    const int*   neighbors = (const int*)d_in[1];
    const void*  maskp     = d_in[2];
    const float* ptm       = (const float*)d_in[3];
    const float* rpu       = (const float*)d_in[4];
    const float* rr        = (const float*)d_in[5];
    const float* vb0       = (const float*)d_in[6];
    const float* vb1       = (const float*)d_in[7];
    const float* vb2       = (const float*)d_in[8];
    const float* qc        = (const float*)d_in[9];
    const float* kc        = (const float*)d_in[10];
    const float* w0p       = (const float*)d_in[11];
    const float* w1p       = (const float*)d_in[12];
    const float* w2p       = (const float*)d_in[13];
    float* out = (float*)d_out;

    int*    flag = (int*)d_ws;
    float4* wtab = (float4*)((char*)d_ws + 1024);   // 64KB table

    detect_mask_kind<<<1, 64, 0, stream>>>((const unsigned int*)maskp, flag);
    compute_weights<<<1, 256, 0, stream>>>(rr, vb0, vb1, vb2,
                                           qc, kc, w0p, w1p, w2p, wtab);
    ge_attn_kernel<<<NV, 256, 0, stream>>>(x, neighbors, maskp, ptm, rpu,
                                           wtab, flag, out);
}

// Round 8
// 357.554 us; speedup vs baseline: 1.0868x; 1.0868x over previous
//
#include <hip/hip_runtime.h>

#define NV   20000
#define MAXN 16

// ---------------------------------------------------------------------------
// Mask dtype detection (bool may arrive as int32 / byte / float32).
// flag: 0 = int32 words, 2 = float32 pattern, 1 = byte bool.
// ---------------------------------------------------------------------------
__global__ void detect_mask_kind(const unsigned int* __restrict__ m,
                                 int* __restrict__ flag) {
    if (threadIdx.x == 0 && blockIdx.x == 0) {
        int allint = 1, allflt = 1;
        #pragma unroll 8
        for (int k = 0; k < 64; ++k) {
            unsigned w = m[k];
            if (!(w == 0u || w == 1u)) allint = 0;
            if (!(w == 0u || w == 0x3F800000u)) allflt = 0;
        }
        *flag = allint ? 0 : (allflt ? 2 : 1);
    }
}

// ---------------------------------------------------------------------------
// One-time weight combine: for each thread slot t=(c,i) produce 8 rows of 8
// (WQ, WK, W0, W1o0, W1o1, W2o0, W2o1, W2o2) = 64 floats, contiguous per t.
// 64KB table, L2-resident, shared by all 20000 main blocks.
// ---------------------------------------------------------------------------
__global__ void compute_weights(const float* __restrict__ rr,
                                const float* __restrict__ vb0,
                                const float* __restrict__ vb1,
                                const float* __restrict__ vb2,
                                const float* __restrict__ qc,
                                const float* __restrict__ kc,
                                const float* __restrict__ w0p,
                                const float* __restrict__ w1p,
                                const float* __restrict__ w2p,
                                float4* __restrict__ wt) {
    const int t = threadIdx.x;
    const int c = t & 31;
    const int i = t >> 5;
    float WQr[8], WKr[8], W0r[8], W1r0[8], W1r1[8], W2r0[8], W2r1[8], W2r2[8];
    #pragma unroll
    for (int j = 0; j < 8; ++j) {
        WQr[j] = 0.f; WKr[j] = 0.f; W0r[j] = 0.f; W1r0[j] = 0.f;
        W1r1[j] = 0.f; W2r0[j] = 0.f; W2r1[j] = 0.f; W2r2[j] = 0.f;
    }
    #pragma unroll
    for (int b = 0; b < 8; ++b) {
        const float qcb = qc[c * 8 + b];
        const float kcb = kc[c * 8 + b];
        const float w0b = w0p[c * 8 + b];
        const float w1b = w1p[c * 8 + b];
        const float w2b = w2p[c * 8 + b];
        const float* rrb = rr  + b * 64  + i * 8;
        const float* z0  = vb0 + b * 64  + i * 8;
        const float* z1  = vb1 + b * 128 + i * 8;   // [b][o][i][j]
        const float* z2  = vb2 + b * 192 + i * 8;
        #pragma unroll
        for (int j = 0; j < 8; ++j) {
            const float r = rrb[j];
            WQr[j]  = fmaf(qcb, r, WQr[j]);
            WKr[j]  = fmaf(kcb, r, WKr[j]);
            W0r[j]  = fmaf(w0b, z0[j],       W0r[j]);
            W1r0[j] = fmaf(w1b, z1[j],       W1r0[j]);
            W1r1[j] = fmaf(w1b, z1[64 + j],  W1r1[j]);
            W2r0[j] = fmaf(w2b, z2[j],       W2r0[j]);
            W2r1[j] = fmaf(w2b, z2[64 + j],  W2r1[j]);
            W2r2[j] = fmaf(w2b, z2[128 + j], W2r2[j]);
        }
    }
    float4* o = wt + t * 16;
    o[ 0] = *(const float4*)&WQr[0];  o[ 1] = *(const float4*)&WQr[4];
    o[ 2] = *(const float4*)&WKr[0];  o[ 3] = *(const float4*)&WKr[4];
    o[ 4] = *(const float4*)&W0r[0];  o[ 5] = *(const float4*)&W0r[4];
    o[ 6] = *(const float4*)&W1r0[0]; o[ 7] = *(const float4*)&W1r0[4];
    o[ 8] = *(const float4*)&W1r1[0]; o[ 9] = *(const float4*)&W1r1[4];
    o[10] = *(const float4*)&W2r0[0]; o[11] = *(const float4*)&W2r0[4];
    o[12] = *(const float4*)&W2r1[0]; o[13] = *(const float4*)&W2r1[4];
    o[14] = *(const float4*)&W2r2[0]; o[15] = *(const float4*)&W2r2[4];
}

__device__ __forceinline__ float dot8a(const float* __restrict__ w,
                                       const float* __restrict__ f) {
    float s = w[0] * f[0];
    #pragma unroll
    for (int j = 1; j < 8; ++j) s = fmaf(w[j], f[j], s);
    return s;
}

__device__ __forceinline__ float dot8f4(const float4& a, const float4& b,
                                        const float* __restrict__ f) {
    return fmaf(a.x, f[0], fmaf(a.y, f[1], fmaf(a.z, f[2], fmaf(a.w, f[3],
           fmaf(b.x, f[4], fmaf(b.y, f[5], fmaf(b.z, f[6], b.w * f[7])))))));
}

// reduce over c: sum across the 32 lanes of each 32-lane half
__device__ __forceinline__ float xred32(float v) {
    v += __shfl_xor(v, 1);
    v += __shfl_xor(v, 2);
    v += __shfl_xor(v, 4);
    v += __shfl_xor(v, 8);
    v += __shfl_xor(v, 16);
    return v;
}

// Phase-split kernel: R3-R7 computed the transported row f'[c,0:8]
// redundantly in all 8 i-slots (64 FMA/neighbor/thread, ~45% of all VALU).
// Phase 1: thread (c,i) computes f' only for neighbors n=2i,2i+1 (128 FMA
// total) and shares via LDS (float2-packed, b64, conflict-free reads).
// Phase 2: per-neighbor dot pipeline unchanged, f read from LDS.
__global__ void __launch_bounds__(256, 3)
ge_attn_kernel(const float* __restrict__ x,
               const int*   __restrict__ neighbors,
               const void*  __restrict__ maskp,
               const float* __restrict__ ptm,
               const float* __restrict__ rpu,
               const float4* __restrict__ wt,
               const int*   __restrict__ mflag,
               float*       __restrict__ out) {
    const int t = threadIdx.x;
    const int c = t & 31;   // channel
    const int i = t >> 5;   // rep index 0..7
    const int w = t >> 6;   // wave id 0..3
    const int mf = *mflag;

    // per-thread combined weight rows: 64 floats, pinned (AGPR/VGPR resident).
    // layout: [WQ 0..7][WK 8..15][W0 16..23][W1o0 24..31][W1o1 32..39]
    //         [W2o0 40..47][W2o1 48..55][W2o2 56..63]
    float W[64];
    {
        const float4* wp = wt + t * 16;
        #pragma unroll
        for (int r = 0; r < 16; ++r) {
            const float4 q = wp[r];
            W[r * 4 + 0] = q.x; W[r * 4 + 1] = q.y;
            W[r * 4 + 2] = q.z; W[r * 4 + 3] = q.w;
        }
        #pragma unroll
        for (int r = 0; r < 64; ++r)
            asm volatile("" : "+v"(W[r]));   // anti-remat / anti-reload pin
    }

    // shared transported features: [n][j-pair][c], float2 per slot = 16KB
    __shared__ __align__(16) float2 fsh[16][4][32];
    __shared__ __align__(16) float  swv[16][4];

    const int v  = blockIdx.x;
    const int vq = v * 16;

    // uniform loads: neighbor ids + mask
    int nb[16];
    unsigned livemask = 0;
    #pragma unroll
    for (int n = 0; n < 16; ++n) {
        nb[n] = neighbors[vq + n];
        int mm;
        if (mf == 0)      mm = (((const int*)maskp)[vq + n] != 0);
        else if (mf == 1) mm = (((const unsigned char*)maskp)[vq + n] != 0);
        else              mm = (((const float*)maskp)[vq + n] != 0.0f);
        if (mm) livemask |= (1u << n);
    }

    // ---- phase 1: this thread transports neighbors n=2i and 2i+1 ----
    #pragma unroll
    for (int sub = 0; sub < 2; ++sub) {
        const int n = 2 * i + sub;
        if (livemask & (1u << n)) {
            float xn[8];
            {
                const float* xnp = x + (size_t)nb[n] * 256 + c * 8;
                *(float4*)&xn[0] = *(const float4*)xnp;
                *(float4*)&xn[4] = *(const float4*)(xnp + 4);
            }
            const float4* P4 = (const float4*)(ptm + (size_t)(vq + n) * 64);
            #pragma unroll
            for (int j2 = 0; j2 < 4; ++j2) {
                const float4 pa0 = P4[4 * j2 + 0], pa1 = P4[4 * j2 + 1]; // row 2*j2
                const float4 pb0 = P4[4 * j2 + 2], pb1 = P4[4 * j2 + 3]; // row 2*j2+1
                float2 fo;
                fo.x = dot8f4(pa0, pa1, xn);
                fo.y = dot8f4(pb0, pb1, xn);
                fsh[n][j2][c] = fo;
            }
        }
    }

    // K[i] for this thread's i, reduced over c in-wave (overlaps phase 1)
    float kreg;
    {
        float xc[8];
        const float* xv = x + (size_t)v * 256 + c * 8;
        *(float4*)&xc[0] = *(const float4*)xv;
        *(float4*)&xc[4] = *(const float4*)(xv + 4);
        kreg = xred32(dot8a(&W[8], xc));
    }

    __syncthreads();   // fsh published

    // ---- phase 2: per-neighbor dots from shared f ----
    float vals[16];
    float acc = 0.f, ssum = 0.f;

    #pragma unroll
    for (int n = 0; n < 16; ++n) {
        if (!(livemask & (1u << n))) continue;
        float f[8];
        #pragma unroll
        for (int j2 = 0; j2 < 4; ++j2) {
            const float2 t2 = fsh[n][j2][c];
            f[2 * j2]     = t2.x;
            f[2 * j2 + 1] = t2.y;
        }
        // score partial: Q[i] over c, relu, i-pair sum in-wave
        const float q = xred32(dot8a(&W[0], f));
        const float r = fmaxf(q + kreg, 0.f);
        const float s = r + __shfl_xor(r, 32);
        if ((t & 63) == 0) swv[n][w] = s;
        // value scalar for this (c,i): 6 dots + u-polynomial
        const float u0 = rpu[(size_t)(vq + n) * 2];
        const float u1 = rpu[(size_t)(vq + n) * 2 + 1];
        const float y0 = dot8a(&W[16], f);
        const float y1 = dot8a(&W[24], f);
        const float y2 = dot8a(&W[32], f);
        const float y3 = dot8a(&W[40], f);
        const float y4 = dot8a(&W[48], f);
        const float y5 = dot8a(&W[56], f);
        float val = fmaf(u0, y1, y0);
        val = fmaf(u1, y2, val);
        val = fmaf(u0 * u0, y3, val);
        val = fmaf(2.f * u0 * u1, y4, val);
        val = fmaf(u1 * u1, y5, val);
        vals[n] = val;
    }

    __syncthreads();   // swv published

    #pragma unroll
    for (int n = 0; n < 16; ++n) {
        if (!(livemask & (1u << n))) continue;
        const float4 sv = *(const float4*)&swv[n][0];
        const float sc = 0.125f * (sv.x + sv.y + sv.z + sv.w);
        ssum += sc;
        acc  = fmaf(sc, vals[n], acc);
    }
    out[(size_t)v * 256 + c * 8 + i] = acc / fmaxf(ssum, 1e-8f);
}

extern "C" void kernel_launch(void* const* d_in, const int* in_sizes, int n_in,
                              void* d_out, int out_size, void* d_ws, size_t ws_size,
                              hipStream_t stream) {
    const float* x         = (const float*)d_in[0];
    const int*   neighbors = (const int*)d_in[1];
    const void*  maskp     = d_in[2];
    const float* ptm       = (const float*)d_in[3];
    const float* rpu       = (const float*)d_in[4];
    const float* rr        = (const float*)d_in[5];
    const float* vb0       = (const float*)d_in[6];
    const float* vb1       = (const float*)d_in[7];
    const float* vb2       = (const float*)d_in[8];
    const float* qc        = (const float*)d_in[9];
    const float* kc        = (const float*)d_in[10];
    const float* w0p       = (const float*)d_in[11];
    const float* w1p       = (const float*)d_in[12];
    const float* w2p       = (const float*)d_in[13];
    float* out = (float*)d_out;

    int*    flag = (int*)d_ws;
    float4* wtab = (float4*)((char*)d_ws + 1024);   // 64KB table

    detect_mask_kind<<<1, 64, 0, stream>>>((const unsigned int*)maskp, flag);
    compute_weights<<<1, 256, 0, stream>>>(rr, vb0, vb1, vb2,
                                           qc, kc, w0p, w1p, w2p, wtab);
    ge_attn_kernel<<<NV, 256, 0, stream>>>(x, neighbors, maskp, ptm, rpu,
                                           wtab, flag, out);
}